// Round 8
// baseline (350.266 us; speedup 1.0000x reference)
//
#include <hip/hip_runtime.h>
#include <hip/hip_bf16.h>
#include <stdint.h>

#define D_IN 4096
#define TOKENS 2048
#define NUM_LATENTS 65536
#define GROUP_DIM 64
#define GROUP_MUL 4
#define IN_GROUPS 64
#define OUT_GROUPS 1024
#define KMID 256   // k' = i*4 + m

typedef __attribute__((ext_vector_type(8))) short short8;
typedef __attribute__((ext_vector_type(4))) float f32x4;

struct alignas(8)  US4 { unsigned short v[4]; };

#define FLAT_BLOCKS 24832   // (4194304 + 2097152 + 65536) / 256

__device__ inline unsigned short f2bf(float f) {
    union { float f; unsigned u; } w{f};
    unsigned r = w.u + 0x7fffu + ((w.u >> 16) & 1u);  // RNE
    return (unsigned short)(r >> 16);
}

__device__ inline void gload_lds16(const void* g, void* l) {
    __builtin_amdgcn_global_load_lds(
        (const __attribute__((address_space(1))) void*)g,
        (__attribute__((address_space(3))) void*)l, 16, 0, 0);
}

// stage3 LDS swizzle: [y][k] bf16 rows of 512B.
// XOR ((y&7)^((y>>3)&7)) into byte bits 4..6 -> 2-way (free) on BOTH the
// scalar write side and the tf read side.
__device__ inline int SWZ(int y, int k) {
    return ((y << 9) + (k << 1)) ^ ((((y & 7) ^ ((y >> 3) & 7)) << 4));
}

// ------------- merged converts: w, x (vector), outer (perm), inner (transpose)
__global__ __launch_bounds__(256) void cvt_all(
    const float* __restrict__ w, const float* __restrict__ x,
    const float* __restrict__ outer, const float* __restrict__ inner,
    unsigned short* __restrict__ w_bf, unsigned short* __restrict__ x_bf,
    unsigned short* __restrict__ o_bf, unsigned short* __restrict__ it_bf) {
    __shared__ float tl[64][65];
    int blk = blockIdx.x;
    const int tid = threadIdx.x;
    if (blk >= FLAT_BLOCKS) {
        // inner[m][i][x][y] f32 -> innT[m][i][y][x^((y&7)<<3)] bf16 (pre-swizzled)
        blk -= FLAT_BLOCKS;                  // m*64+i
        const float* src = inner + (size_t)blk * 4096;
        #pragma unroll
        for (int p = 0; p < 4; ++p) {
            int idx = p * 1024 + tid * 4;
            int xx = idx >> 6, y = idx & 63;
            f32x4 v = *(const f32x4*)(src + idx);
            #pragma unroll
            for (int j = 0; j < 4; ++j) tl[xx][y + j] = v[j];
        }
        __syncthreads();
        unsigned short* dst = it_bf + (size_t)blk * 4096;
        #pragma unroll
        for (int p = 0; p < 4; ++p) {
            int idx = p * 1024 + tid * 4;
            int y = idx >> 6, x0 = idx & 63;
            US4 o;
            #pragma unroll
            for (int j = 0; j < 4; ++j) o.v[j] = f2bf(tl[x0 + j][y]);
            *(US4*)(dst + y * 64 + (x0 ^ ((y & 7) << 3))) = o;
        }
        return;
    }
    int s = blk * 256 + tid;                 // f32x4 slot
    if (s < 4194304) {                       // w
        f32x4 v = *(const f32x4*)(w + (size_t)s * 4);
        US4 o;
        #pragma unroll
        for (int j = 0; j < 4; ++j) o.v[j] = f2bf(v[j]);
        *(US4*)(w_bf + (size_t)s * 4) = o;
    } else if (s < 6291456) {                // x
        int t = s - 4194304;
        f32x4 v = *(const f32x4*)(x + (size_t)t * 4);
        US4 o;
        #pragma unroll
        for (int j = 0; j < 4; ++j) o.v[j] = f2bf(v[j]);
        *(US4*)(x_bf + (size_t)t * 4) = o;
    } else {                                 // outer: [o][m][i] -> [o][i*4+m]
        int t0 = (s - 6291456) * 4;
        int o = t0 >> 8, r = t0 & 255, m = r >> 6, i = r & 63;
        f32x4 v = *(const f32x4*)(outer + t0);
        #pragma unroll
        for (int j = 0; j < 4; ++j)
            o_bf[(o << 8) + (i + j) * 4 + m] = f2bf(v[j]);
    }
}

// ------- fused stage 1+2: h = x@W^T+b (regs) -> t[b][i*4+m][y] ------------
__global__ __launch_bounds__(256, 2) void gemm_fused(
    const unsigned short* __restrict__ A,   // x_bf  [2048][4096]
    const unsigned short* __restrict__ B,   // w_bf  [4096][4096]
    const float* __restrict__ bias,
    const unsigned short* __restrict__ IT,  // innT [4][64][64][64] bf16, x pre-swizzled
    unsigned short* __restrict__ T)         // [2048][256][64] bf16
{
    __shared__ unsigned short smem[40960];  // 80 KB -> 2 blocks/CU
    unsigned short* inn = smem + 32768;

    const int tid = threadIdx.x;
    const int lane = tid & 63;
    const int w = tid >> 6;
    const int wm = w >> 1, wn = w & 1;
    int bx = blockIdx.x;
    bx = (bx & 7) * 64 + (bx >> 3);   // XCD swizzle: B panel 4MB = one L2
    const int m0 = (bx & 15) * 128;
    const int n0 = (bx >> 4) * 128;
    const int i0 = n0 >> 6;

    const int lr = lane & 15;
    const int hi = lane >> 4;
    const int lk = hi * 8;

    f32x4 acc[4][4] = {};

    // LDS[row][u] holds global (row, u ^ (row&7)); u = 16B unit 0..7 in a row
    auto STAGE = [&](int buf, int k0) {
        #pragma unroll
        for (int c = 0; c < 4; ++c) {
            int f = c * 2048 + tid * 8;
            int r = f >> 6;
            int colsw = ((((f >> 3) & 7) ^ (r & 7)) << 3);
            gload_lds16(A + (size_t)(m0 + r) * D_IN + k0 + colsw, smem + buf * 16384 + f);
            gload_lds16(B + (size_t)(n0 + r) * D_IN + k0 + colsw, smem + buf * 16384 + 8192 + f);
        }
    };
    auto COMPUTE = [&](int buf) {
        const unsigned short* as = smem + buf * 16384;
        const unsigned short* bs = as + 8192;
        #pragma unroll
        for (int kk = 0; kk < 2; ++kk) {
            short8 a[4], b[4];
            #pragma unroll
            for (int mi = 0; mi < 4; ++mi) {
                int row = wm * 64 + mi * 16 + lr;
                a[mi] = *(const short8*)(as + (row << 6) + ((((kk << 2) + hi) ^ (lr & 7)) << 3));
            }
            #pragma unroll
            for (int ni = 0; ni < 4; ++ni) {
                int row = wn * 64 + ni * 16 + lr;
                b[ni] = *(const short8*)(bs + (row << 6) + ((((kk << 2) + hi) ^ (lr & 7)) << 3));
            }
            __builtin_amdgcn_s_setprio(1);
            #pragma unroll
            for (int mi = 0; mi < 4; ++mi)
                #pragma unroll
                for (int ni = 0; ni < 4; ++ni)   // swapped: D=[col][tok]
                    acc[mi][ni] = __builtin_amdgcn_mfma_f32_16x16x32_bf16(b[ni], a[mi], acc[mi][ni], 0, 0, 0);
            __builtin_amdgcn_s_setprio(0);
        }
    };

    STAGE(0, 0);
    #pragma unroll 1
    for (int t = 0; t < 64; ++t) {
        asm volatile("s_waitcnt vmcnt(0)" ::: "memory");
        __builtin_amdgcn_s_barrier();
        __builtin_amdgcn_sched_barrier(0);
        if (t < 63) STAGE((t + 1) & 1, (t + 1) * 64);
        COMPUTE(t & 1);
        __builtin_amdgcn_sched_barrier(0);
    }

    // ---- epilogue A: h (+bias, bf16) -> smem[0..16383], swizzled, US4 stores
    #pragma unroll
    for (int ni = 0; ni < 4; ++ni) {
        int col0 = wn * 64 + ni * 16 + hi * 4;
        f32x4 bv = *(const f32x4*)(bias + n0 + col0);
        #pragma unroll
        for (int mi = 0; mi < 4; ++mi) {
            int tok = wm * 64 + mi * 16 + lr;
            US4 o;
            #pragma unroll
            for (int j = 0; j < 4; ++j) o.v[j] = f2bf(acc[mi][ni][j] + bv[j]);
            *(US4*)(smem + tok * 128 + (col0 ^ ((tok & 7) << 3))) = o;
        }
    }

    // ---- epilogue B: per m, t[tok][(i0+wn)*4+m][y] = h[tok][i,:] @ innT^T
    for (int m = 0; m < 4; ++m) {
        #pragma unroll
        for (int c = 0; c < 4; ++c) {
            int e = c * 2048 + tid * 8;
            int i_loc = e >> 12, rem = e & 4095;
            gload_lds16(IT + ((size_t)(m * 64 + i0 + i_loc) << 12) + rem, inn + e);
        }
        asm volatile("s_waitcnt vmcnt(0)" ::: "memory");
        __syncthreads();

        f32x4 acc2[4][4] = {};
        #pragma unroll
        for (int kk = 0; kk < 2; ++kk) {
            short8 a[4], b2[4];
            #pragma unroll
            for (int mi = 0; mi < 4; ++mi) {
                int tok = wm * 64 + mi * 16 + lr;
                a[mi] = *(const short8*)(smem + tok * 128 + ((wn * 64 + kk * 32 + lk) ^ ((tok & 7) << 3)));
            }
            #pragma unroll
            for (int ni = 0; ni < 4; ++ni) {
                int y = ni * 16 + lr;
                b2[ni] = *(const short8*)(inn + wn * 4096 + y * 64 + ((kk * 32 + lk) ^ ((y & 7) << 3)));
            }
            #pragma unroll
            for (int mi = 0; mi < 4; ++mi)
                #pragma unroll
                for (int ni = 0; ni < 4; ++ni)   // swapped: D=[y][tok]
                    acc2[mi][ni] = __builtin_amdgcn_mfma_f32_16x16x32_bf16(b2[ni], a[mi], acc2[mi][ni], 0, 0, 0);
        }

        const int kp = (i0 + wn) * 4 + m;
        #pragma unroll
        for (int mi = 0; mi < 4; ++mi) {
            int tok = m0 + wm * 64 + mi * 16 + lr;
            unsigned short* trow = T + ((size_t)tok * KMID + kp) * 64;
            #pragma unroll
            for (int ni = 0; ni < 4; ++ni) {
                int y0 = ni * 16 + hi * 4;
                US4 o;
                #pragma unroll
                for (int j = 0; j < 4; ++j) o.v[j] = f2bf(acc2[mi][ni][j]);
                *(US4*)(trow + y0) = o;
            }
        }
        __syncthreads();
    }
}

// ---------------- stage 3: out[b][o][y] = sum_k outerB[o][k] * t[b][k][y]
// 256-thr half-token blocks (grid 4096): 4 waves x 128 o each, acc[4][8].
// 2 blocks/CU resident -> stage/store of one overlaps MFMA of the other.
// Both halves of a token land consecutively on the same XCD (T L2 reuse).
__global__ __launch_bounds__(256, 2) void stage3(
    const unsigned short* __restrict__ T,   // [2048][256][64] bf16
    const unsigned short* __restrict__ Ob,  // [1024][256] bf16
    float* __restrict__ out)                // [2048][65536] f32
{
    __shared__ char ts[32768];
    const int tid = threadIdx.x;
    const int lane = tid & 63;
    const int w = tid >> 6;          // 0..3
    const int bx = blockIdx.x;
    const int xcd = bx & 7, j = bx >> 3;
    const int b = xcd * 256 + (j >> 1);
    const int half = j & 1;
    const int lr = lane & 15;
    const int hi = lane >> 4;

    // stage full t_b (16384 elems) -> LDS transposed [y][k], swizzled
    {
        const unsigned short* src = T + (size_t)b * (KMID * 64);
        #pragma unroll
        for (int c = 0; c < 8; ++c) {
            int e = c * 2048 + tid * 8;
            int k = e >> 6, y = e & 63;
            short8 v = __builtin_nontemporal_load((const short8*)(src + e));
            #pragma unroll
            for (int jj = 0; jj < 8; ++jj)
                *(unsigned short*)(ts + SWZ(y + jj, k)) = (unsigned short)v[jj];
        }
    }
    __syncthreads();

    const int o_base = half * 512 + w * 128;
    f32x4 acc[4][8] = {};   // [ni_y][mi_o]
    for (int kt = 0; kt < 8; ++kt) {
        short8 tf[4], of[8];
        #pragma unroll
        for (int ni = 0; ni < 4; ++ni)
            tf[ni] = *(const short8*)(ts + SWZ(ni * 16 + lr, kt * 32 + hi * 8));
        #pragma unroll
        for (int mi = 0; mi < 8; ++mi)
            of[mi] = *(const short8*)(Ob + ((size_t)(o_base + mi * 16 + lr) << 8) + kt * 32 + hi * 8);
        #pragma unroll
        for (int ni = 0; ni < 4; ++ni)
            #pragma unroll
            for (int mi = 0; mi < 8; ++mi)
                acc[ni][mi] = __builtin_amdgcn_mfma_f32_16x16x32_bf16(tf[ni], of[mi], acc[ni][mi], 0, 0, 0);
    }

    float* ob = out + (size_t)b * NUM_LATENTS;
    #pragma unroll
    for (int ni = 0; ni < 4; ++ni) {
        #pragma unroll
        for (int mi = 0; mi < 8; ++mi) {
            int o = o_base + mi * 16 + lr;
            int y = ni * 16 + hi * 4;
            __builtin_nontemporal_store(acc[ni][mi], (f32x4*)(ob + (o << 6) + y));
        }
    }
}

extern "C" void kernel_launch(void* const* d_in, const int* in_sizes, int n_in,
                              void* d_out, int out_size, void* d_ws, size_t ws_size,
                              hipStream_t stream) {
    const float* x     = (const float*)d_in[0];
    const float* pre_w = (const float*)d_in[1];
    const float* pre_b = (const float*)d_in[2];
    const float* inner = (const float*)d_in[3];
    const float* outer = (const float*)d_in[4];
    float* out = (float*)d_out;

    char* ws = (char*)d_ws;
    unsigned short* x_bf = (unsigned short*)ws;  ws += (size_t)TOKENS * D_IN * 2;
    unsigned short* w_bf = (unsigned short*)ws;  ws += (size_t)D_IN * D_IN * 2;
    unsigned short* o_bf = (unsigned short*)ws;  ws += (size_t)OUT_GROUPS * KMID * 2;
    unsigned short* t_bf = (unsigned short*)ws;  ws += (size_t)TOKENS * KMID * 64 * 2;
    unsigned short* it_bf = (unsigned short*)ws; ws += (size_t)GROUP_MUL * IN_GROUPS * 64 * 64 * 2;

    cvt_all<<<FLAT_BLOCKS + GROUP_MUL * IN_GROUPS, 256, 0, stream>>>(
        pre_w, x, outer, inner, w_bf, x_bf, o_bf, it_bf);

    gemm_fused<<<512, 256, 0, stream>>>(x_bf, w_bf, pre_b, it_bf, t_bf);
    stage3<<<4096, 256, 0, stream>>>(t_bf, o_bf, out);
}

// Round 9
// 315.763 us; speedup vs baseline: 1.1093x; 1.1093x over previous
//
#include <hip/hip_runtime.h>
#include <hip/hip_bf16.h>
#include <stdint.h>

#define D_IN 4096
#define TOKENS 2048
#define NUM_LATENTS 65536
#define GROUP_DIM 64
#define GROUP_MUL 4
#define IN_GROUPS 64
#define OUT_GROUPS 1024
#define KMID 256   // k' = i*4 + m

typedef __attribute__((ext_vector_type(8))) short short8;
typedef __attribute__((ext_vector_type(4))) float f32x4;

struct alignas(8)  US4 { unsigned short v[4]; };

#define FLAT_BLOCKS 24832   // (4194304 + 2097152 + 65536) / 256

__device__ inline unsigned short f2bf(float f) {
    union { float f; unsigned u; } w{f};
    unsigned r = w.u + 0x7fffu + ((w.u >> 16) & 1u);  // RNE
    return (unsigned short)(r >> 16);
}

__device__ inline void gload_lds16(const void* g, void* l) {
    __builtin_amdgcn_global_load_lds(
        (const __attribute__((address_space(1))) void*)g,
        (__attribute__((address_space(3))) void*)l, 16, 0, 0);
}

// stage3 LDS swizzle: [y][k] bf16 rows of 512B.
// XOR ((y&7)^((y>>3)&7)) into byte bits 4..6 -> 2-way (free) on BOTH the
// scalar write side and the tf read side.
__device__ inline int SWZ(int y, int k) {
    return ((y << 9) + (k << 1)) ^ ((((y & 7) ^ ((y >> 3) & 7)) << 4));
}

// ------------- merged converts: w, x (vector), outer (perm), inner (transpose)
__global__ __launch_bounds__(256) void cvt_all(
    const float* __restrict__ w, const float* __restrict__ x,
    const float* __restrict__ outer, const float* __restrict__ inner,
    unsigned short* __restrict__ w_bf, unsigned short* __restrict__ x_bf,
    unsigned short* __restrict__ o_bf, unsigned short* __restrict__ it_bf) {
    __shared__ float tl[64][65];
    int blk = blockIdx.x;
    const int tid = threadIdx.x;
    if (blk >= FLAT_BLOCKS) {
        // inner[m][i][x][y] f32 -> innT[m][i][y][x^((y&7)<<3)] bf16 (pre-swizzled)
        blk -= FLAT_BLOCKS;                  // m*64+i
        const float* src = inner + (size_t)blk * 4096;
        #pragma unroll
        for (int p = 0; p < 4; ++p) {
            int idx = p * 1024 + tid * 4;
            int xx = idx >> 6, y = idx & 63;
            f32x4 v = *(const f32x4*)(src + idx);
            #pragma unroll
            for (int j = 0; j < 4; ++j) tl[xx][y + j] = v[j];
        }
        __syncthreads();
        unsigned short* dst = it_bf + (size_t)blk * 4096;
        #pragma unroll
        for (int p = 0; p < 4; ++p) {
            int idx = p * 1024 + tid * 4;
            int y = idx >> 6, x0 = idx & 63;
            US4 o;
            #pragma unroll
            for (int j = 0; j < 4; ++j) o.v[j] = f2bf(tl[x0 + j][y]);
            *(US4*)(dst + y * 64 + (x0 ^ ((y & 7) << 3))) = o;
        }
        return;
    }
    int s = blk * 256 + tid;                 // f32x4 slot
    if (s < 4194304) {                       // w
        f32x4 v = *(const f32x4*)(w + (size_t)s * 4);
        US4 o;
        #pragma unroll
        for (int j = 0; j < 4; ++j) o.v[j] = f2bf(v[j]);
        *(US4*)(w_bf + (size_t)s * 4) = o;
    } else if (s < 6291456) {                // x
        int t = s - 4194304;
        f32x4 v = *(const f32x4*)(x + (size_t)t * 4);
        US4 o;
        #pragma unroll
        for (int j = 0; j < 4; ++j) o.v[j] = f2bf(v[j]);
        *(US4*)(x_bf + (size_t)t * 4) = o;
    } else {                                 // outer: [o][m][i] -> [o][i*4+m]
        int t0 = (s - 6291456) * 4;
        int o = t0 >> 8, r = t0 & 255, m = r >> 6, i = r & 63;
        f32x4 v = *(const f32x4*)(outer + t0);
        #pragma unroll
        for (int j = 0; j < 4; ++j)
            o_bf[(o << 8) + (i + j) * 4 + m] = f2bf(v[j]);
    }
}

// ------- fused stage 1+2: h = x@W^T+b (regs) -> t[b][i*4+m][y] ------------
// 512 threads / 8 waves per 128x128 tile: 16 waves/CU (4/SIMD) at grid 512.
// Wave tile 64x32 (acc[4][2]). Same LDS (80KB), same DMA traffic as 4-wave.
__global__ __launch_bounds__(512, 4) void gemm_fused(
    const unsigned short* __restrict__ A,   // x_bf  [2048][4096]
    const unsigned short* __restrict__ B,   // w_bf  [4096][4096]
    const float* __restrict__ bias,
    const unsigned short* __restrict__ IT,  // innT [4][64][64][64] bf16, x pre-swizzled
    unsigned short* __restrict__ T)         // [2048][256][64] bf16
{
    // As0[0..8191] Bs0[..16383] As1[..24575] Bs1[..32767] | inn[32768..40959]
    // (elem indices; h tile 128x128 overlays As0+Bs0 after the main loop)
    __shared__ unsigned short smem[40960];  // 80 KB -> 2 blocks/CU
    unsigned short* inn = smem + 32768;

    const int tid = threadIdx.x;
    const int lane = tid & 63;
    const int w = tid >> 6;          // 0..7
    const int wm = w >> 2;           // 0..1 : 64-token half
    const int wn = w & 3;            // 0..3 : 32-col quarter
    int bx = blockIdx.x;
    bx = (bx & 7) * 64 + (bx >> 3);  // XCD swizzle: B panel 4MB = one L2
    const int m0 = (bx & 15) * 128;
    const int n0 = (bx >> 4) * 128;
    const int i0 = n0 >> 6;

    const int lr = lane & 15;
    const int hi = lane >> 4;
    const int lk = hi * 8;

    f32x4 acc[4][2] = {};

    // LDS[row][u] holds global (row, u ^ (row&7)); u = 16B unit 0..7 in a row
    auto STAGE = [&](int buf, int k0) {
        #pragma unroll
        for (int c = 0; c < 2; ++c) {
            int f = c * 4096 + tid * 8;
            int r = f >> 6;
            int colsw = ((((f >> 3) & 7) ^ (r & 7)) << 3);
            gload_lds16(A + (size_t)(m0 + r) * D_IN + k0 + colsw, smem + buf * 16384 + f);
            gload_lds16(B + (size_t)(n0 + r) * D_IN + k0 + colsw, smem + buf * 16384 + 8192 + f);
        }
    };
    auto COMPUTE = [&](int buf) {
        const unsigned short* as = smem + buf * 16384;
        const unsigned short* bs = as + 8192;
        #pragma unroll
        for (int kk = 0; kk < 2; ++kk) {
            short8 a[4], b[2];
            #pragma unroll
            for (int mi = 0; mi < 4; ++mi) {
                int row = wm * 64 + mi * 16 + lr;
                a[mi] = *(const short8*)(as + (row << 6) + ((((kk << 2) + hi) ^ (lr & 7)) << 3));
            }
            #pragma unroll
            for (int ni = 0; ni < 2; ++ni) {
                int row = wn * 32 + ni * 16 + lr;
                b[ni] = *(const short8*)(bs + (row << 6) + ((((kk << 2) + hi) ^ (lr & 7)) << 3));
            }
            __builtin_amdgcn_s_setprio(1);
            #pragma unroll
            for (int mi = 0; mi < 4; ++mi)
                #pragma unroll
                for (int ni = 0; ni < 2; ++ni)   // swapped: D=[col][tok]
                    acc[mi][ni] = __builtin_amdgcn_mfma_f32_16x16x32_bf16(b[ni], a[mi], acc[mi][ni], 0, 0, 0);
            __builtin_amdgcn_s_setprio(0);
        }
    };

    STAGE(0, 0);
    #pragma unroll 1
    for (int t = 0; t < 64; ++t) {
        asm volatile("s_waitcnt vmcnt(0)" ::: "memory");
        __builtin_amdgcn_s_barrier();
        __builtin_amdgcn_sched_barrier(0);
        if (t < 63) STAGE((t + 1) & 1, (t + 1) * 64);
        COMPUTE(t & 1);
        __builtin_amdgcn_sched_barrier(0);
    }

    // ---- epilogue A: h (+bias, bf16) -> smem[0..16383], swizzled, US4 stores
    #pragma unroll
    for (int ni = 0; ni < 2; ++ni) {
        int col0 = wn * 32 + ni * 16 + hi * 4;
        f32x4 bv = *(const f32x4*)(bias + n0 + col0);
        #pragma unroll
        for (int mi = 0; mi < 4; ++mi) {
            int tok = wm * 64 + mi * 16 + lr;
            US4 o;
            #pragma unroll
            for (int j = 0; j < 4; ++j) o.v[j] = f2bf(acc[mi][ni][j] + bv[j]);
            *(US4*)(smem + tok * 128 + (col0 ^ ((tok & 7) << 3))) = o;
        }
    }

    // ---- epilogue B: per m, t[tok][(i0+i_loc)*4+m][y] = h[tok][i,:] @ innT^T
    const int i_loc = wn >> 1;       // 0..1
    const int yh = (wn & 1) * 32;    // y-half
    for (int m = 0; m < 4; ++m) {
        #pragma unroll
        for (int c = 0; c < 2; ++c) {
            int e = c * 4096 + tid * 8;
            int i_l = e >> 12, rem = e & 4095;
            gload_lds16(IT + ((size_t)(m * 64 + i0 + i_l) << 12) + rem, inn + e);
        }
        asm volatile("s_waitcnt vmcnt(0)" ::: "memory");
        __syncthreads();   // inn ready; (m==0) h visible

        f32x4 acc2[4][2] = {};
        #pragma unroll
        for (int kk = 0; kk < 2; ++kk) {
            short8 a[4], b2[2];
            #pragma unroll
            for (int mi = 0; mi < 4; ++mi) {
                int tok = wm * 64 + mi * 16 + lr;
                a[mi] = *(const short8*)(smem + tok * 128 + ((i_loc * 64 + kk * 32 + lk) ^ ((tok & 7) << 3)));
            }
            #pragma unroll
            for (int ni = 0; ni < 2; ++ni) {
                int y = yh + ni * 16 + lr;
                b2[ni] = *(const short8*)(inn + i_loc * 4096 + y * 64 + ((kk * 32 + lk) ^ ((y & 7) << 3)));
            }
            #pragma unroll
            for (int mi = 0; mi < 4; ++mi)
                #pragma unroll
                for (int ni = 0; ni < 2; ++ni)   // swapped: D=[y][tok]
                    acc2[mi][ni] = __builtin_amdgcn_mfma_f32_16x16x32_bf16(b2[ni], a[mi], acc2[mi][ni], 0, 0, 0);
        }

        const int kp = (i0 + i_loc) * 4 + m;
        #pragma unroll
        for (int mi = 0; mi < 4; ++mi) {
            int tok = m0 + wm * 64 + mi * 16 + lr;
            unsigned short* trow = T + ((size_t)tok * KMID + kp) * 64;
            #pragma unroll
            for (int ni = 0; ni < 2; ++ni) {
                int y0 = yh + ni * 16 + hi * 4;
                US4 o;
                #pragma unroll
                for (int j = 0; j < 4; ++j) o.v[j] = f2bf(acc2[mi][ni][j]);
                *(US4*)(trow + y0) = o;
            }
        }
        __syncthreads();   // protect inn before next m's DMA
    }
}

// ---------------- stage 3: out[b][o][y] = sum_k outerB[o][k] * t[b][k][y]
// one block per token (512 thr, 8 waves x 128 o). t^T staged in swizzled LDS.
// MFMA operands swapped (A = t^T, B = outer) -> D[y][o], f32x4 y-contig stores.
__global__ __launch_bounds__(512) void stage3(
    const unsigned short* __restrict__ T,   // [2048][256][64] bf16
    const unsigned short* __restrict__ Ob,  // [1024][256] bf16
    float* __restrict__ out)                // [2048][65536] f32
{
    __shared__ char ts[32768];
    const int tid = threadIdx.x;
    const int lane = tid & 63;
    const int w = tid >> 6;
    int bx = blockIdx.x;
    const int b = (bx & 7) * 256 + (bx >> 3);   // XCD swizzle
    const int lr = lane & 15;
    const int hi = lane >> 4;

    {
        const unsigned short* src = T + (size_t)b * (KMID * 64);
        #pragma unroll
        for (int c = 0; c < 4; ++c) {
            int e = c * 4096 + tid * 8;
            int k = e >> 6, y = e & 63;
            short8 v = __builtin_nontemporal_load((const short8*)(src + e));
            #pragma unroll
            for (int j = 0; j < 8; ++j)
                *(unsigned short*)(ts + SWZ(y + j, k)) = (unsigned short)v[j];
        }
    }
    __syncthreads();

    const int o_base = w * 128;
    f32x4 acc[4][8] = {};   // [ni_y][mi_o]
    for (int kt = 0; kt < 8; ++kt) {
        short8 tf[4], of[8];
        #pragma unroll
        for (int ni = 0; ni < 4; ++ni)
            tf[ni] = *(const short8*)(ts + SWZ(ni * 16 + lr, kt * 32 + hi * 8));
        #pragma unroll
        for (int mi = 0; mi < 8; ++mi)
            of[mi] = *(const short8*)(Ob + ((size_t)(o_base + mi * 16 + lr) << 8) + kt * 32 + hi * 8);
        #pragma unroll
        for (int ni = 0; ni < 4; ++ni)
            #pragma unroll
            for (int mi = 0; mi < 8; ++mi)
                acc[ni][mi] = __builtin_amdgcn_mfma_f32_16x16x32_bf16(tf[ni], of[mi], acc[ni][mi], 0, 0, 0);
    }

    float* ob = out + (size_t)b * NUM_LATENTS;
    #pragma unroll
    for (int ni = 0; ni < 4; ++ni) {
        #pragma unroll
        for (int mi = 0; mi < 8; ++mi) {
            int o = o_base + mi * 16 + lr;
            int y = ni * 16 + hi * 4;
            __builtin_nontemporal_store(acc[ni][mi], (f32x4*)(ob + (o << 6) + y));
        }
    }
}

extern "C" void kernel_launch(void* const* d_in, const int* in_sizes, int n_in,
                              void* d_out, int out_size, void* d_ws, size_t ws_size,
                              hipStream_t stream) {
    const float* x     = (const float*)d_in[0];
    const float* pre_w = (const float*)d_in[1];
    const float* pre_b = (const float*)d_in[2];
    const float* inner = (const float*)d_in[3];
    const float* outer = (const float*)d_in[4];
    float* out = (float*)d_out;

    char* ws = (char*)d_ws;
    unsigned short* x_bf = (unsigned short*)ws;  ws += (size_t)TOKENS * D_IN * 2;
    unsigned short* w_bf = (unsigned short*)ws;  ws += (size_t)D_IN * D_IN * 2;
    unsigned short* o_bf = (unsigned short*)ws;  ws += (size_t)OUT_GROUPS * KMID * 2;
    unsigned short* t_bf = (unsigned short*)ws;  ws += (size_t)TOKENS * KMID * 64 * 2;
    unsigned short* it_bf = (unsigned short*)ws; ws += (size_t)GROUP_MUL * IN_GROUPS * 64 * 64 * 2;

    cvt_all<<<FLAT_BLOCKS + GROUP_MUL * IN_GROUPS, 256, 0, stream>>>(
        pre_w, x, outer, inner, w_bf, x_bf, o_bf, it_bf);

    gemm_fused<<<512, 512, 0, stream>>>(x_bf, w_bf, pre_b, it_bf, t_bf);
    stage3<<<2048, 512, 0, stream>>>(t_bf, o_bf, out);
}